// Round 7
// baseline (710.001 us; speedup 1.0000x reference)
//
#include <hip/hip_runtime.h>
#include <stdint.h>

#define TT 128
#define BSZ 512
#define HID 512
#define KDIM 512
#define BH (BSZ*HID)   // 262144 neurons

// ---------------- fp32 tiled GEMM: C[m][n] = sum_k A[m][k] * W[n][k] + bias[n] --------
// 256x128 block tile, 256 threads, 16x8 microtile (DS-instr/fma 25% lower than 8x8 —
// DS pipe is the measured co-bottleneck), BK=16, double-buffered LDS, one barrier/tile.
// NUMERICS CONTRACT (bit-exact vs np ref, absmax 0.0 in R2/R5/R6): per output element
// the reduction is ONE sequential fma chain over k ascending, fp32. Do not reorder/split.
__global__ __launch_bounds__(256, 2) void gemm_f32(
    const float* __restrict__ A, const float* __restrict__ W,
    const float* __restrict__ bias, float* __restrict__ C) {
  __shared__ float As[2][16][260];   // [k][m], +4/row bank shift
  __shared__ float Bs[2][16][132];   // [k][n]
  const int t  = threadIdx.x;
  const int m0 = blockIdx.y * 256;
  const int n0 = blockIdx.x * 128;
  const int tx = t & 15;          // n: cols {tx*4..+3} and {64+tx*4..+3}
  const int ty = t >> 4;          // m: rows ty*16..ty*16+15
  const int r0 = t >> 2;          // staging row 0..63 (+64/+128/+192)
  const int kg4 = (t & 3) * 4;    // k row group within 16-wide k tile

  float4 acc0[16], acc1[16];
  #pragma unroll
  for (int i = 0; i < 16; ++i) {
    acc0[i] = (float4){0.f,0.f,0.f,0.f};
    acc1[i] = (float4){0.f,0.f,0.f,0.f};
  }

  const float* Ap = A + (size_t)(m0 + r0) * KDIM + kg4;
  const float* Wp = W + (size_t)(n0 + r0) * KDIM + kg4;

  float4 a0 = *(const float4*)Ap;
  float4 a1 = *(const float4*)(Ap + (size_t)64  * KDIM);
  float4 a2 = *(const float4*)(Ap + (size_t)128 * KDIM);
  float4 a3 = *(const float4*)(Ap + (size_t)192 * KDIM);
  float4 w0 = *(const float4*)Wp;
  float4 w1 = *(const float4*)(Wp + (size_t)64 * KDIM);

  #define STAGE(BUF) do { \
    As[BUF][kg4+0][r0]     = a0.x; As[BUF][kg4+1][r0]     = a0.y; As[BUF][kg4+2][r0]     = a0.z; As[BUF][kg4+3][r0]     = a0.w; \
    As[BUF][kg4+0][r0+64]  = a1.x; As[BUF][kg4+1][r0+64]  = a1.y; As[BUF][kg4+2][r0+64]  = a1.z; As[BUF][kg4+3][r0+64]  = a1.w; \
    As[BUF][kg4+0][r0+128] = a2.x; As[BUF][kg4+1][r0+128] = a2.y; As[BUF][kg4+2][r0+128] = a2.z; As[BUF][kg4+3][r0+128] = a2.w; \
    As[BUF][kg4+0][r0+192] = a3.x; As[BUF][kg4+1][r0+192] = a3.y; As[BUF][kg4+2][r0+192] = a3.z; As[BUF][kg4+3][r0+192] = a3.w; \
    Bs[BUF][kg4+0][r0]     = w0.x; Bs[BUF][kg4+1][r0]     = w0.y; Bs[BUF][kg4+2][r0]     = w0.z; Bs[BUF][kg4+3][r0]     = w0.w; \
    Bs[BUF][kg4+0][r0+64]  = w1.x; Bs[BUF][kg4+1][r0+64]  = w1.y; Bs[BUF][kg4+2][r0+64]  = w1.z; Bs[BUF][kg4+3][r0+64]  = w1.w; \
  } while (0)

  STAGE(0);

  // 8 fma on one A value against both B float4 fragments, no copies
  #define FMA8(AV, I) \
    acc0[I].x = __builtin_fmaf(AV, bf0.x, acc0[I].x); \
    acc0[I].y = __builtin_fmaf(AV, bf0.y, acc0[I].y); \
    acc0[I].z = __builtin_fmaf(AV, bf0.z, acc0[I].z); \
    acc0[I].w = __builtin_fmaf(AV, bf0.w, acc0[I].w); \
    acc1[I].x = __builtin_fmaf(AV, bf1.x, acc1[I].x); \
    acc1[I].y = __builtin_fmaf(AV, bf1.y, acc1[I].y); \
    acc1[I].z = __builtin_fmaf(AV, bf1.z, acc1[I].z); \
    acc1[I].w = __builtin_fmaf(AV, bf1.w, acc1[I].w);

  int cur = 0;
  for (int k0 = 0; k0 < KDIM; k0 += 16) {
    // One barrier/tile: makes buf[cur] writes visible AND protects buf[cur^1]
    // (read two iterations ago, re-staged below).
    __syncthreads();
    const bool more = (k0 + 16 < KDIM);
    if (more) {
      a0 = *(const float4*)(Ap + k0 + 16);
      a1 = *(const float4*)(Ap + (size_t)64  * KDIM + k0 + 16);
      a2 = *(const float4*)(Ap + (size_t)128 * KDIM + k0 + 16);
      a3 = *(const float4*)(Ap + (size_t)192 * KDIM + k0 + 16);
      w0 = *(const float4*)(Wp + k0 + 16);
      w1 = *(const float4*)(Wp + (size_t)64 * KDIM + k0 + 16);
    }

    #pragma unroll
    for (int kk = 0; kk < 16; ++kk) {
      const float4 bf0 = *(const float4*)&Bs[cur][kk][tx*4];       // 2-way, free
      const float4 bf1 = *(const float4*)&Bs[cur][kk][64 + tx*4];
      const float4 af0 = *(const float4*)&As[cur][kk][ty*16];      // 16-lane broadcast
      const float4 af1 = *(const float4*)&As[cur][kk][ty*16 + 4];
      const float4 af2 = *(const float4*)&As[cur][kk][ty*16 + 8];
      const float4 af3 = *(const float4*)&As[cur][kk][ty*16 + 12];
      FMA8(af0.x, 0)  FMA8(af0.y, 1)  FMA8(af0.z, 2)  FMA8(af0.w, 3)
      FMA8(af1.x, 4)  FMA8(af1.y, 5)  FMA8(af1.z, 6)  FMA8(af1.w, 7)
      FMA8(af2.x, 8)  FMA8(af2.y, 9)  FMA8(af2.z, 10) FMA8(af2.w, 11)
      FMA8(af3.x, 12) FMA8(af3.y, 13) FMA8(af3.z, 14) FMA8(af3.w, 15)
    }

    if (more) STAGE(cur ^ 1);
    cur ^= 1;
  }
  #undef STAGE
  #undef FMA8

  // epilogue: + bias (ref adds b once to xp — identical), coalesced float4 stores
  const float4 bv0 = *(const float4*)&bias[n0 + tx*4];
  const float4 bv1 = *(const float4*)&bias[n0 + 64 + tx*4];
  #pragma unroll
  for (int i = 0; i < 16; ++i) {
    const float4 v0 = {acc0[i].x + bv0.x, acc0[i].y + bv0.y, acc0[i].z + bv0.z, acc0[i].w + bv0.w};
    const float4 v1 = {acc1[i].x + bv1.x, acc1[i].y + bv1.y, acc1[i].z + bv1.z, acc1[i].w + bv1.w};
    float* cp = C + (size_t)(m0 + ty*16 + i) * HID + n0;
    *(float4*)(cp + tx*4)      = v0;
    *(float4*)(cp + 64 + tx*4) = v1;
  }
}

// ---------------- LIF scan (bit-identical to np fp32 reference given xp) ----------------
__device__ __forceinline__ float lif_step(float y, float v[4], float av[4]) {
  float as3 = 0.f;
  #pragma unroll
  for (int l = 0; l < 4; ++l) {
    float vv = v[l];
    float accv = 0.f, accs = 0.f;
    #pragma unroll
    for (int k = 0; k < 4; ++k) {
      const float d = y - vv;                        // round(inp - v)
      vv = __builtin_fmaf(d, 0.5f, vv);              // round(v + d*0.5): d*0.5 exact
      const float spk = (vv >= 1.0f) ? 1.0f : 0.0f;  // v-1>=0 <=> v>=1 (exact)
      vv -= spk;                                     // soft reset
      accv += vv;
      accs += spk;
    }
    v[l] = vv;
    const float a = accv * 0.25f;                    // exact /4
    av[l] = a;
    y = a;                                           // next layer consumes avg_v
    as3 = accs;
  }
  return as3;
}

// TWO neurons per thread (float2): two independent LIF chains give in-wave ILP that
// hides the ~4-cyc VALU dependence latency of the substep chain; memory instrs halve.
// 4-deep t-prefetch keeps ~4 KB/wave in flight for HBM latency.
__global__ __launch_bounds__(256) void lif_scan(
    const float* __restrict__ xp, float* __restrict__ outp, float* __restrict__ vstate,
    int tc, int first, int last) {
  const int gid = blockIdx.x * 256 + threadIdx.x;   // pair index, 0..BH/2-1
  const int S2 = BH / 2;
  const float2* p = (const float2*)xp + gid;
  float2* op = (float2*)outp + gid;
  float2* vs = (float2*)vstate;                     // [4][S2]

  float v0[4], v1[4];
  if (first) {
    #pragma unroll
    for (int l = 0; l < 4; ++l) { v0[l] = 0.f; v1[l] = 0.f; }
  } else {
    #pragma unroll
    for (int l = 0; l < 4; ++l) {
      const float2 vv = vs[(size_t)l * S2 + gid];
      v0[l] = vv.x; v1[l] = vv.y;
    }
  }
  float av0[4] = {0.f,0.f,0.f,0.f}, av1[4] = {0.f,0.f,0.f,0.f};

  if ((tc & 3) == 0 && tc >= 8) {
    float2 curb[4];
    #pragma unroll
    for (int i = 0; i < 4; ++i) curb[i] = p[(size_t)i * S2];
    for (int t = 0; t + 4 < tc; t += 4) {
      float2 nxt[4];
      #pragma unroll
      for (int i = 0; i < 4; ++i) nxt[i] = p[(size_t)(i + 4) * S2];  // in flight over compute
      #pragma unroll
      for (int i = 0; i < 4; ++i) {
        const float s0 = lif_step(curb[i].x, v0, av0);   // two independent chains -> ILP
        const float s1 = lif_step(curb[i].y, v1, av1);
        op[(size_t)i * S2] = (float2){s0 * 0.25f, s1 * 0.25f};
      }
      #pragma unroll
      for (int i = 0; i < 4; ++i) curb[i] = nxt[i];
      p += (size_t)4 * S2; op += (size_t)4 * S2;
    }
    #pragma unroll
    for (int i = 0; i < 4; ++i) {                    // tail group, already in registers
      const float s0 = lif_step(curb[i].x, v0, av0);
      const float s1 = lif_step(curb[i].y, v1, av1);
      op[(size_t)i * S2] = (float2){s0 * 0.25f, s1 * 0.25f};
    }
  } else {
    for (int t = 0; t < tc; ++t) {
      const float2 cv = *p;
      const float s0 = lif_step(cv.x, v0, av0);
      const float s1 = lif_step(cv.y, v1, av1);
      *op = (float2){s0 * 0.25f, s1 * 0.25f};
      p += S2; op += S2;
    }
  }

  if (last) {
    #pragma unroll
    for (int l = 0; l < 4; ++l) vs[(size_t)l * S2 + gid] = (float2){av0[l], av1[l]};
  } else {
    #pragma unroll
    for (int l = 0; l < 4; ++l) vs[(size_t)l * S2 + gid] = (float2){v0[l], v1[l]};
  }
}

extern "C" void kernel_launch(void* const* d_in, const int* in_sizes, int n_in,
                              void* d_out, int out_size, void* d_ws, size_t ws_size,
                              hipStream_t stream) {
  const float* x = (const float*)d_in[0];   // [128,512,512] fp32
  const float* W = (const float*)d_in[1];   // [512,512] fp32
  const float* b = (const float*)d_in[2];   // [512] fp32
  float* out    = (float*)d_out;            // [128,512,512] avg spikes (fp32)
  float* states = out + (size_t)TT * BH;    // [4,512,512] final avg_v; also chunk-carry v

  int tc = TT;                              // xp chunk: tc MiB of ws
  while (tc > 1 && (size_t)tc * BH * 4ull > ws_size) tc >>= 1;
  float* xp = (float*)d_ws;
  const int nc = TT / tc;

  for (int c = 0; c < nc; ++c) {
    hipLaunchKernelGGL(gemm_f32, dim3(HID / 128, tc * BSZ / 256), dim3(256), 0, stream,
                       x + (size_t)c * tc * BH, W, b, xp);
    hipLaunchKernelGGL(lif_scan, dim3(BH / 512), dim3(256), 0, stream,
                       xp, out + (size_t)c * tc * BH, states,
                       tc, c == 0 ? 1 : 0, c == nc - 1 ? 1 : 0);
  }
}

// Round 8
// 659.835 us; speedup vs baseline: 1.0760x; 1.0760x over previous
//
#include <hip/hip_runtime.h>
#include <stdint.h>

#define TT 128
#define BSZ 512
#define HID 512
#define KDIM 512
#define BH (BSZ*HID)   // 262144 neurons

// ---------------- fp32 tiled GEMM: C[m][n] = sum_k A[m][k] * W[n][k] + bias[n] --------
// 256x128 block tile, 256 threads, 16x8 microtile, BK=16, double-buffered LDS.
// NO second __launch_bounds__ arg: R7 showed (256,2) caps VGPR at 128 -> acc spills to
// scratch (WRITE_SIZE 131->457 MB). This kernel NEEDS ~190 VGPRs (128 acc + staging).
// NUMERICS CONTRACT (bit-exact vs np ref, absmax 0.0 R2/R5/R6/R7): per output element
// the reduction is ONE sequential fma chain over k ascending, fp32. Do not reorder/split.
__global__ __launch_bounds__(256) void gemm_f32(
    const float* __restrict__ A, const float* __restrict__ W,
    const float* __restrict__ bias, float* __restrict__ C) {
  __shared__ float As[2][16][260];   // [k][m], +4/row bank shift
  __shared__ float Bs[2][16][132];   // [k][n]
  const int t = threadIdx.x;

  // XCD swizzle: consecutive block ids round-robin XCDs (id%8). Remap so one XCD's
  // sequence sweeps all 4 n-tiles of an m-group before advancing m -> A rows served
  // from that XCD's L2 (512 KB tile working set << 4 MiB).
  const int flat  = blockIdx.y * gridDim.x + blockIdx.x;
  const int total = gridDim.x * gridDim.y;
  int mb, nb;
  if ((total & 31) == 0 && gridDim.x == 4) {
    const int xcd = flat & 7, seq = flat >> 3;
    nb = seq & 3;
    mb = (seq >> 2) * 8 + xcd;
  } else { mb = blockIdx.y; nb = blockIdx.x; }
  const int m0 = mb * 256;
  const int n0 = nb * 128;

  const int tx = t & 15;          // n: cols {tx*4..+3} and {64+tx*4..+3}
  const int ty = t >> 4;          // m: rows ty*16..ty*16+15
  const int r0 = t >> 2;          // staging row 0..63 (+64/+128/+192)
  const int kg4 = (t & 3) * 4;    // k row group within 16-wide k tile

  float4 acc0[16], acc1[16];
  #pragma unroll
  for (int i = 0; i < 16; ++i) {
    acc0[i] = (float4){0.f,0.f,0.f,0.f};
    acc1[i] = (float4){0.f,0.f,0.f,0.f};
  }

  const float* Ap = A + (size_t)(m0 + r0) * KDIM + kg4;
  const float* Wp = W + (size_t)(n0 + r0) * KDIM + kg4;

  float4 a0 = *(const float4*)Ap;
  float4 a1 = *(const float4*)(Ap + (size_t)64  * KDIM);
  float4 a2 = *(const float4*)(Ap + (size_t)128 * KDIM);
  float4 a3 = *(const float4*)(Ap + (size_t)192 * KDIM);
  float4 w0 = *(const float4*)Wp;
  float4 w1 = *(const float4*)(Wp + (size_t)64 * KDIM);

  #define STAGE(BUF) do { \
    As[BUF][kg4+0][r0]     = a0.x; As[BUF][kg4+1][r0]     = a0.y; As[BUF][kg4+2][r0]     = a0.z; As[BUF][kg4+3][r0]     = a0.w; \
    As[BUF][kg4+0][r0+64]  = a1.x; As[BUF][kg4+1][r0+64]  = a1.y; As[BUF][kg4+2][r0+64]  = a1.z; As[BUF][kg4+3][r0+64]  = a1.w; \
    As[BUF][kg4+0][r0+128] = a2.x; As[BUF][kg4+1][r0+128] = a2.y; As[BUF][kg4+2][r0+128] = a2.z; As[BUF][kg4+3][r0+128] = a2.w; \
    As[BUF][kg4+0][r0+192] = a3.x; As[BUF][kg4+1][r0+192] = a3.y; As[BUF][kg4+2][r0+192] = a3.z; As[BUF][kg4+3][r0+192] = a3.w; \
    Bs[BUF][kg4+0][r0]     = w0.x; Bs[BUF][kg4+1][r0]     = w0.y; Bs[BUF][kg4+2][r0]     = w0.z; Bs[BUF][kg4+3][r0]     = w0.w; \
    Bs[BUF][kg4+0][r0+64]  = w1.x; Bs[BUF][kg4+1][r0+64]  = w1.y; Bs[BUF][kg4+2][r0+64]  = w1.z; Bs[BUF][kg4+3][r0+64]  = w1.w; \
  } while (0)

  STAGE(0);

  #define FMA8(AV, I) \
    acc0[I].x = __builtin_fmaf(AV, bf0.x, acc0[I].x); \
    acc0[I].y = __builtin_fmaf(AV, bf0.y, acc0[I].y); \
    acc0[I].z = __builtin_fmaf(AV, bf0.z, acc0[I].z); \
    acc0[I].w = __builtin_fmaf(AV, bf0.w, acc0[I].w); \
    acc1[I].x = __builtin_fmaf(AV, bf1.x, acc1[I].x); \
    acc1[I].y = __builtin_fmaf(AV, bf1.y, acc1[I].y); \
    acc1[I].z = __builtin_fmaf(AV, bf1.z, acc1[I].z); \
    acc1[I].w = __builtin_fmaf(AV, bf1.w, acc1[I].w);

  int cur = 0;
  for (int k0 = 0; k0 < KDIM; k0 += 16) {
    // One barrier/tile: makes buf[cur] writes visible AND protects buf[cur^1]
    // (read two iterations ago, re-staged below).
    __syncthreads();
    const bool more = (k0 + 16 < KDIM);
    if (more) {
      a0 = *(const float4*)(Ap + k0 + 16);
      a1 = *(const float4*)(Ap + (size_t)64  * KDIM + k0 + 16);
      a2 = *(const float4*)(Ap + (size_t)128 * KDIM + k0 + 16);
      a3 = *(const float4*)(Ap + (size_t)192 * KDIM + k0 + 16);
      w0 = *(const float4*)(Wp + k0 + 16);
      w1 = *(const float4*)(Wp + (size_t)64 * KDIM + k0 + 16);
    }

    #pragma unroll
    for (int kk = 0; kk < 16; ++kk) {
      const float4 bf0 = *(const float4*)&Bs[cur][kk][tx*4];       // 2-way, free
      const float4 bf1 = *(const float4*)&Bs[cur][kk][64 + tx*4];
      const float4 af0 = *(const float4*)&As[cur][kk][ty*16];      // 16-lane broadcast
      const float4 af1 = *(const float4*)&As[cur][kk][ty*16 + 4];
      const float4 af2 = *(const float4*)&As[cur][kk][ty*16 + 8];
      const float4 af3 = *(const float4*)&As[cur][kk][ty*16 + 12];
      FMA8(af0.x, 0)  FMA8(af0.y, 1)  FMA8(af0.z, 2)  FMA8(af0.w, 3)
      FMA8(af1.x, 4)  FMA8(af1.y, 5)  FMA8(af1.z, 6)  FMA8(af1.w, 7)
      FMA8(af2.x, 8)  FMA8(af2.y, 9)  FMA8(af2.z, 10) FMA8(af2.w, 11)
      FMA8(af3.x, 12) FMA8(af3.y, 13) FMA8(af3.z, 14) FMA8(af3.w, 15)
    }

    if (more) STAGE(cur ^ 1);
    cur ^= 1;
  }
  #undef STAGE
  #undef FMA8

  // epilogue: + bias (ref adds b once to xp — identical), coalesced float4 stores
  const float4 bv0 = *(const float4*)&bias[n0 + tx*4];
  const float4 bv1 = *(const float4*)&bias[n0 + 64 + tx*4];
  #pragma unroll
  for (int i = 0; i < 16; ++i) {
    const float4 v0 = {acc0[i].x + bv0.x, acc0[i].y + bv0.y, acc0[i].z + bv0.z, acc0[i].w + bv0.w};
    const float4 v1 = {acc1[i].x + bv1.x, acc1[i].y + bv1.y, acc1[i].z + bv1.z, acc1[i].w + bv1.w};
    float* cp = C + (size_t)(m0 + ty*16 + i) * HID + n0;
    *(float4*)(cp + tx*4)      = v0;
    *(float4*)(cp + 64 + tx*4) = v1;
  }
}

// ---------------- LIF scan (bit-identical to np fp32 reference given xp) ----------------
// Critical-path-shortened substep: compute (vv-1) IN PARALLEL with the compare, then
// cndmask. s ? vv-1 : vv  ==  vv - spk exactly; s ? accs+1 : accs == accs + spk exactly.
__device__ __forceinline__ float lif_step(float y, float v[4], float av[4]) {
  float as3 = 0.f;
  #pragma unroll
  for (int l = 0; l < 4; ++l) {
    float vv = v[l];
    float accv = 0.f, accs = 0.f;
    #pragma unroll
    for (int k = 0; k < 4; ++k) {
      const float d = y - vv;                  // chain
      vv = __builtin_fmaf(d, 0.5f, vv);        // chain (d*0.5 exact => matches ref)
      const bool s = (vv >= 1.0f);             // chain
      const float t1 = vv - 1.0f;              // parallel
      vv = s ? t1 : vv;                        // chain (cndmask)
      accs = s ? accs + 1.0f : accs;           // off-chain
      accv += vv;                              // off-chain
    }
    v[l] = vv;
    const float a = accv * 0.25f;              // exact /4
    av[l] = a;
    y = a;                                     // next layer consumes avg_v
    as3 = accs;
  }
  return as3;
}

// TWO neurons per thread (float2): independent chains give ILP; 4-deep t-prefetch.
__global__ __launch_bounds__(256) void lif_scan(
    const float* __restrict__ xp, float* __restrict__ outp, float* __restrict__ vstate,
    int tc, int first, int last) {
  const int gid = blockIdx.x * 256 + threadIdx.x;   // pair index, 0..BH/2-1
  const int S2 = BH / 2;
  const float2* p = (const float2*)xp + gid;
  float2* op = (float2*)outp + gid;
  float2* vs = (float2*)vstate;                     // [4][S2]

  float v0[4], v1[4];
  if (first) {
    #pragma unroll
    for (int l = 0; l < 4; ++l) { v0[l] = 0.f; v1[l] = 0.f; }
  } else {
    #pragma unroll
    for (int l = 0; l < 4; ++l) {
      const float2 vv = vs[(size_t)l * S2 + gid];
      v0[l] = vv.x; v1[l] = vv.y;
    }
  }
  float av0[4] = {0.f,0.f,0.f,0.f}, av1[4] = {0.f,0.f,0.f,0.f};

  if ((tc & 3) == 0 && tc >= 8) {
    float2 curb[4];
    #pragma unroll
    for (int i = 0; i < 4; ++i) curb[i] = p[(size_t)i * S2];
    for (int t = 0; t + 4 < tc; t += 4) {
      float2 nxt[4];
      #pragma unroll
      for (int i = 0; i < 4; ++i) nxt[i] = p[(size_t)(i + 4) * S2];  // in flight over compute
      #pragma unroll
      for (int i = 0; i < 4; ++i) {
        const float s0 = lif_step(curb[i].x, v0, av0);
        const float s1 = lif_step(curb[i].y, v1, av1);
        op[(size_t)i * S2] = (float2){s0 * 0.25f, s1 * 0.25f};
      }
      #pragma unroll
      for (int i = 0; i < 4; ++i) curb[i] = nxt[i];
      p += (size_t)4 * S2; op += (size_t)4 * S2;
    }
    #pragma unroll
    for (int i = 0; i < 4; ++i) {                    // tail group, already in registers
      const float s0 = lif_step(curb[i].x, v0, av0);
      const float s1 = lif_step(curb[i].y, v1, av1);
      op[(size_t)i * S2] = (float2){s0 * 0.25f, s1 * 0.25f};
    }
  } else {
    for (int t = 0; t < tc; ++t) {
      const float2 cv = *p;
      const float s0 = lif_step(cv.x, v0, av0);
      const float s1 = lif_step(cv.y, v1, av1);
      *op = (float2){s0 * 0.25f, s1 * 0.25f};
      p += S2; op += S2;
    }
  }

  if (last) {
    #pragma unroll
    for (int l = 0; l < 4; ++l) vs[(size_t)l * S2 + gid] = (float2){av0[l], av1[l]};
  } else {
    #pragma unroll
    for (int l = 0; l < 4; ++l) vs[(size_t)l * S2 + gid] = (float2){v0[l], v1[l]};
  }
}

extern "C" void kernel_launch(void* const* d_in, const int* in_sizes, int n_in,
                              void* d_out, int out_size, void* d_ws, size_t ws_size,
                              hipStream_t stream) {
  const float* x = (const float*)d_in[0];   // [128,512,512] fp32
  const float* W = (const float*)d_in[1];   // [512,512] fp32
  const float* b = (const float*)d_in[2];   // [512] fp32
  float* out    = (float*)d_out;            // [128,512,512] avg spikes (fp32)
  float* states = out + (size_t)TT * BH;    // [4,512,512] final avg_v; also chunk-carry v

  int tc = TT;                              // xp chunk: tc MiB of ws
  while (tc > 1 && (size_t)tc * BH * 4ull > ws_size) tc >>= 1;
  float* xp = (float*)d_ws;
  const int nc = TT / tc;

  for (int c = 0; c < nc; ++c) {
    hipLaunchKernelGGL(gemm_f32, dim3(HID / 128, tc * BSZ / 256), dim3(256), 0, stream,
                       x + (size_t)c * tc * BH, W, b, xp);
    hipLaunchKernelGGL(lif_scan, dim3(BH / 512), dim3(256), 0, stream,
                       xp, out + (size_t)c * tc * BH, states,
                       tc, c == 0 ? 1 : 0, c == nc - 1 ? 1 : 0);
  }
}